// Round 2
// baseline (124.730 us; speedup 1.0000x reference)
//
#include <hip/hip_runtime.h>
#include <hip/hip_bf16.h>

typedef __attribute__((ext_vector_type(8))) short short8;
typedef __attribute__((ext_vector_type(4))) float f32x4;

#define LDST 72   // bf16 elements per LDS row (144B, 16B-aligned, bank-friendly)
#define MFMA16(a, b, c) __builtin_amdgcn_mfma_f32_16x16x32_bf16(a, b, c, 0, 0, 0)

__device__ __forceinline__ unsigned short f2bf(float x) {
  unsigned u = __float_as_uint(x);
  return (unsigned short)((u + 0x7fffu + ((u >> 16) & 1u)) >> 16);  // RNE
}
__device__ __forceinline__ float bf2f(unsigned short h) {
  return __uint_as_float(((unsigned)h) << 16);
}

// One block = one (batch, window). 256 threads = 4 waves; wave w owns output
// rows m0 = w*16 .. +15. Roll(-32) folded into global row index; roll(+32) on
// output is the inverse, so window row i maps to global row p=(n*64+32+i)&8191
// for both loads and the x store.
//
// Q is loaded straight into registers (each wave only needs its own 16 rows).
// K and V (hi/lo bf16 split) are staged in LDS; V is stored transposed with an
// XOR octet swizzle. P goes through a DEDICATED LDS buffer with a full
// __syncthreads() between write and read (R1's replay divergence implicated
// the barrier-free aliased P-bounce).
__global__ __launch_bounds__(256, 3)
void swin64_attn(const float* __restrict__ qg, const float* __restrict__ kg,
                 const float* __restrict__ vg, const float* __restrict__ tbl,
                 float* __restrict__ ox, float* __restrict__ oa) {
  __shared__ unsigned short Khi[64 * LDST], Klo[64 * LDST];
  __shared__ unsigned short Vhi[64 * LDST], Vlo[64 * LDST];   // transposed [c][j]
  __shared__ unsigned short Pb[64 * LDST];
  __shared__ float btab[128];

  const int t = threadIdx.x;
  const int b = blockIdx.x >> 7;
  const int n = blockIdx.x & 127;
  const int l = t & 63;
  const int w = t >> 6;
  const int r15 = l & 15;
  const int g4 = l >> 4;
  const int m0 = w * 16;

  if (t < 127) btab[t] = tbl[t];

  // ---- stage K (hi/lo, row-major stride 72) and V (transposed + XOR-swizzled)
#pragma unroll
  for (int s = 0; s < 2; ++s) {
    const int seg = t + s * 256;      // 0..511: 64 rows x 8 col-octets
    const int row = seg >> 3;
    const int c8 = seg & 7;
    const int p = (n * 64 + 32 + row) & 8191;
    const size_t g = ((size_t)b * 8192 + (size_t)p) * 64 + (size_t)(c8 * 8);

    {
      const float4 a0 = *(const float4*)(kg + g);
      const float4 a1 = *(const float4*)(kg + g + 4);
      const float f[8] = {a0.x, a0.y, a0.z, a0.w, a1.x, a1.y, a1.z, a1.w};
      short8 h8, l8;
#pragma unroll
      for (int i = 0; i < 8; ++i) {
        const unsigned short h = f2bf(f[i]);
        h8[i] = (short)h;
        l8[i] = (short)f2bf(f[i] - bf2f(h));
      }
      *(short8*)&Khi[row * LDST + c8 * 8] = h8;
      *(short8*)&Klo[row * LDST + c8 * 8] = l8;
    }
    {
      const float4 a0 = *(const float4*)(vg + g);
      const float4 a1 = *(const float4*)(vg + g + 4);
      const float f[8] = {a0.x, a0.y, a0.z, a0.w, a1.x, a1.y, a1.z, a1.w};
#pragma unroll
      for (int i = 0; i < 8; ++i) {
        const int c = c8 * 8 + i;          // channel -> Vt row
        const unsigned short h = f2bf(f[i]);
        const unsigned short lo2 = f2bf(f[i] - bf2f(h));
        // j (= row) stored at 8-block (j>>3) ^ ((c>>3)&7): keeps frag
        // contiguity, spreads scatter-write banks (~2-way).
        const int idx = c * LDST + ((((row >> 3) ^ ((c >> 3) & 7)) << 3) | (row & 7));
        Vhi[idx] = h;
        Vlo[idx] = lo2;
      }
    }
  }

  // ---- Q fragments straight from global (wave-private rows), hi/lo in regs
  short8 qh0, qh1, ql0, ql1;
  {
    const int qrow = (n * 64 + 32 + m0 + r15) & 8191;
    const float* qp = qg + ((size_t)b * 8192 + (size_t)qrow) * 64;
    const float4 a0 = *(const float4*)(qp + g4 * 8);
    const float4 a1 = *(const float4*)(qp + g4 * 8 + 4);
    const float4 a2 = *(const float4*)(qp + 32 + g4 * 8);
    const float4 a3 = *(const float4*)(qp + 32 + g4 * 8 + 4);
    const float f0[8] = {a0.x, a0.y, a0.z, a0.w, a1.x, a1.y, a1.z, a1.w};
    const float f1[8] = {a2.x, a2.y, a2.z, a2.w, a3.x, a3.y, a3.z, a3.w};
#pragma unroll
    for (int i = 0; i < 8; ++i) {
      const unsigned short h0 = f2bf(f0[i]);
      qh0[i] = (short)h0;
      ql0[i] = (short)f2bf(f0[i] - bf2f(h0));
      const unsigned short h1 = f2bf(f1[i]);
      qh1[i] = (short)h1;
      ql1[i] = (short)f2bf(f1[i] - bf2f(h1));
    }
  }
  __syncthreads();

  // fragment loaders: lane l -> row (rb + l&15), 8 contiguous k at kb*32+(l>>4)*8
  auto ldf = [&](const unsigned short* a, int rb, int kb) -> short8 {
    return *(const short8*)&a[(rb + r15) * LDST + kb * 32 + g4 * 8];
  };
  auto ldv = [&](const unsigned short* a, int rb, int kb) -> short8 {
    const int c = rb + r15;
    const int blk = (kb * 4 + g4) ^ ((c >> 3) & 7);
    return *(const short8*)&a[c * LDST + blk * 8];
  };

  // ---- QK^T with hi/lo split (drop lo*lo): S accurate to ~2^-17 rel
  f32x4 acc[4];
#pragma unroll
  for (int nt = 0; nt < 4; ++nt) {
    const short8 kh0 = ldf(Khi, nt * 16, 0), kh1 = ldf(Khi, nt * 16, 1);
    const short8 kl0 = ldf(Klo, nt * 16, 0), kl1 = ldf(Klo, nt * 16, 1);
    f32x4 a = {0.f, 0.f, 0.f, 0.f};
    a = MFMA16(qh0, kh0, a);
    a = MFMA16(qh1, kh1, a);
    a = MFMA16(ql0, kh0, a);
    a = MFMA16(ql1, kh1, a);
    a = MFMA16(qh0, kl0, a);
    a = MFMA16(qh1, kl1, a);
    acc[nt] = a;
  }

  // ---- scale + bias + shift-mask; D layout: row = m0 + g4*4 + r, col = nt*16 + r15
  float sv[4][4];  // [nt][r]
#pragma unroll
  for (int nt = 0; nt < 4; ++nt) {
#pragma unroll
    for (int r = 0; r < 4; ++r) {
      const int i = m0 + g4 * 4 + r;
      const int j = nt * 16 + r15;
      float sx = acc[nt][r] * 0.125f + btab[i - j + 63];
      if (n == 127 && ((i < 32) != (j < 32))) sx -= 100.f;
      sv[nt][r] = sx;
    }
  }

  // ---- row softmax: reduce over 16 lanes of the row-group (masks 1,2,4,8)
  float mx[4], rinv[4], pr[4][4];
#pragma unroll
  for (int r = 0; r < 4; ++r) {
    float m2 = fmaxf(fmaxf(sv[0][r], sv[1][r]), fmaxf(sv[2][r], sv[3][r]));
    m2 = fmaxf(m2, __shfl_xor(m2, 1));
    m2 = fmaxf(m2, __shfl_xor(m2, 2));
    m2 = fmaxf(m2, __shfl_xor(m2, 4));
    m2 = fmaxf(m2, __shfl_xor(m2, 8));
    mx[r] = m2;
  }
#pragma unroll
  for (int nt = 0; nt < 4; ++nt) {
#pragma unroll
    for (int r = 0; r < 4; ++r) pr[nt][r] = __expf(sv[nt][r] - mx[r]);
  }
#pragma unroll
  for (int r = 0; r < 4; ++r) {
    float s2 = pr[0][r] + pr[1][r] + pr[2][r] + pr[3][r];
    s2 += __shfl_xor(s2, 1);
    s2 += __shfl_xor(s2, 2);
    s2 += __shfl_xor(s2, 4);
    s2 += __shfl_xor(s2, 8);
    rinv[r] = 1.f / s2;
  }

  // ---- write attn (normalized, f32) + unnormalized bf16 P into dedicated LDS
  float* ap = oa + (size_t)blockIdx.x * 4096;
#pragma unroll
  for (int nt = 0; nt < 4; ++nt) {
#pragma unroll
    for (int r = 0; r < 4; ++r) {
      const int i = m0 + g4 * 4 + r;
      const int j = nt * 16 + r15;
      Pb[i * LDST + j] = f2bf(pr[nt][r]);
      ap[i * 64 + j] = pr[nt][r] * rinv[r];
    }
  }
  __syncthreads();   // hard fence between P writes and P fragment reads

  // ---- PV: x = P * (Vhi + Vlo), scale rows by 1/sum at the end
  const short8 pa0 = ldf(Pb, m0, 0), pa1 = ldf(Pb, m0, 1);
#pragma unroll
  for (int ct = 0; ct < 4; ++ct) {
    const short8 vh0 = ldv(Vhi, ct * 16, 0), vh1 = ldv(Vhi, ct * 16, 1);
    const short8 vl0 = ldv(Vlo, ct * 16, 0), vl1 = ldv(Vlo, ct * 16, 1);
    f32x4 a = {0.f, 0.f, 0.f, 0.f};
    a = MFMA16(pa0, vh0, a);
    a = MFMA16(pa1, vh1, a);
    a = MFMA16(pa0, vl0, a);
    a = MFMA16(pa1, vl1, a);
#pragma unroll
    for (int r = 0; r < 4; ++r) {
      const int i = m0 + g4 * 4 + r;
      const int p2 = (n * 64 + 32 + i) & 8191;
      ox[((size_t)b * 8192 + (size_t)p2) * 64 + ct * 16 + r15] = a[r] * rinv[r];
    }
  }
}

extern "C" void kernel_launch(void* const* d_in, const int* in_sizes, int n_in,
                              void* d_out, int out_size, void* d_ws, size_t ws_size,
                              hipStream_t stream) {
  const float* q = (const float*)d_in[0];
  const float* k = (const float*)d_in[1];
  const float* v = (const float*)d_in[2];
  const float* tbl = (const float*)d_in[3];
  float* ox = (float*)d_out;
  float* oa = ox + (size_t)64 * 8192 * 64;  // x first, then attn
  swin64_attn<<<dim3(8192), dim3(256), 0, stream>>>(q, k, v, tbl, ox, oa);
}